// Round 10
// baseline (262.209 us; speedup 1.0000x reference)
//
#include <hip/hip_runtime.h>

#define DIM 128
#define LN_EPS 1e-5f

typedef __attribute__((ext_vector_type(8))) short bf16x8;
typedef __attribute__((ext_vector_type(4))) float f32x4;

static __device__ __forceinline__ unsigned short f2bf(float f) {
    unsigned int u = __builtin_bit_cast(unsigned int, f);
    u += 0x7fffu + ((u >> 16) & 1u);  // round-to-nearest-even
    return (unsigned short)(u >> 16);
}
static __device__ __forceinline__ float bf2f_lo(unsigned int u) {
    return __builtin_bit_cast(float, u << 16);
}
static __device__ __forceinline__ float bf2f_hi(unsigned int u) {
    return __builtin_bit_cast(float, u & 0xffff0000u);
}

// --------------------- fused: x fp32->bf16, W transpose+cvt, degree count
__global__ __launch_bounds__(256) void cvt_count_kernel(const float* __restrict__ X,
                                                        unsigned short* __restrict__ Y, int n4,
                                                        int nx4b,
                                                        const float* __restrict__ W1,
                                                        const float* __restrict__ W2,
                                                        unsigned short* __restrict__ Wt1,
                                                        unsigned short* __restrict__ Wt2,
                                                        const int* __restrict__ dst,
                                                        int* __restrict__ counts, int E) {
    int b = blockIdx.x;
    if (b < nx4b) {
        int i = b * 256 + threadIdx.x;
        if (i < n4) {
            float4 v = ((const float4*)X)[i];
            ushort4 o;
            o.x = f2bf(v.x); o.y = f2bf(v.y); o.z = f2bf(v.z); o.w = f2bf(v.w);
            ((ushort4*)Y)[i] = o;
        }
    } else if (b < nx4b + 128) {
        int elem = (b - nx4b) * 256 + threadIdx.x;  // [0, 32768)
        int which = elem >> 14;
        int rest = elem & 16383;
        int c = rest >> 7;
        int k = rest & 127;
        const float* W = which ? W2 : W1;
        unsigned short* Wt = which ? Wt2 : Wt1;
        Wt[c * 128 + k] = f2bf(W[k * 128 + c]);
    } else {
        int e = (b - nx4b - 128) * 256 + threadIdx.x;
        if (e < E) atomicAdd(&counts[dst[e]], 1);
    }
}

// ------------------------------------------------- scan pass 1 (+dinv compute)
__global__ __launch_bounds__(256) void scan1_kernel(const int* __restrict__ counts,
                                                    int* __restrict__ tmp,
                                                    int* __restrict__ bsums,
                                                    float* __restrict__ dinv, int n) {
    __shared__ int ts[256];
    int tid = threadIdx.x;
    int base = blockIdx.x * 1024 + tid * 4;
    int v[4];
#pragma unroll
    for (int j = 0; j < 4; ++j) {
        int i = base + j;
        v[j] = (i < n) ? counts[i] : 0;
        if (i < n) dinv[i] = rsqrtf((float)(v[j] + 1));  // +1 self-loop
    }
    int s = v[0] + v[1] + v[2] + v[3];
    ts[tid] = s;
    __syncthreads();
    for (int off = 1; off < 256; off <<= 1) {
        int t2 = (tid >= off) ? ts[tid - off] : 0;
        __syncthreads();
        ts[tid] += t2;
        __syncthreads();
    }
    int excl = ts[tid] - s;
    int pre = excl;
#pragma unroll
    for (int j = 0; j < 4; ++j) {
        int i = base + j;
        if (i < n) tmp[i] = pre;
        pre += v[j];
    }
    if (tid == 255) bsums[blockIdx.x] = ts[255];
}

// ------------------- scan pass 2+3 merged
__global__ __launch_bounds__(256) void scan3_kernel(const int* __restrict__ tmp,
                                                    const int* __restrict__ bsums,
                                                    int* __restrict__ rowptr,
                                                    int* __restrict__ cursor,
                                                    int n, int E, int nb) {
    __shared__ int s_add;
    if (threadIdx.x < 64) {
        int lane = threadIdx.x;
        int v = (lane < nb) ? bsums[lane] : 0;
        int x = v;
#pragma unroll
        for (int off = 1; off < 64; off <<= 1) {
            int y = __shfl_up(x, off);
            if (lane >= off) x += y;
        }
        int excl = x - v;
        int mine = __builtin_amdgcn_readlane(excl, blockIdx.x);
        if (lane == 0) s_add = mine;
    }
    __syncthreads();
    int add = s_add;
    int base = blockIdx.x * 1024 + threadIdx.x * 4;
#pragma unroll
    for (int j = 0; j < 4; ++j) {
        int i = base + j;
        if (i < n) {
            int val = tmp[i] + add;
            rowptr[i] = val;
            cursor[i] = val;
        }
    }
    if (blockIdx.x == 0 && threadIdx.x == 0) rowptr[n] = E;
}

// ---------------------------------------------------------------- CSR fill
__global__ __launch_bounds__(256) void fill_kernel(const int* __restrict__ src,
                                                   const int* __restrict__ dst,
                                                   int* __restrict__ cursor,
                                                   unsigned short* __restrict__ colsrc, int E) {
    int e = blockIdx.x * 256 + threadIdx.x;
    if (e < E) {
        int p = atomicAdd(&cursor[dst[e]], 1);
        colsrc[p] = (unsigned short)src[e];
    }
}

// ---------------------------------------------------------------- MFMA GEMM
// Wt staged in LDS; H written PLANE-MAJOR: plane q = cols [32q,32q+32),
// row s of plane q at ushort offset (q*n + s)*32 (64B per row-quarter; one
// 128B L2 line = two consecutive rows of the same plane).
__global__ __launch_bounds__(256) void gemm_mfma_kernel(const unsigned short* __restrict__ A,
                                                        const unsigned short* __restrict__ Bt,
                                                        const float* __restrict__ dinv,
                                                        unsigned short* __restrict__ H,
                                                        int n, int ntiles) {
    __shared__ unsigned short Wlds[128 * 136];

    for (int u = threadIdx.x; u < 2048; u += 256) {
        int row = u >> 4;
        int sub = u & 15;
        *(bf16x8*)&Wlds[row * 136 + sub * 8] = *(const bf16x8*)(Bt + row * 128 + sub * 8);
    }
    __syncthreads();

    int wid = threadIdx.x >> 6;
    int lane = threadIdx.x & 63;
    int tile = blockIdx.x * 4 + wid;
    if (tile >= ntiles) tile = ntiles - 1;  // no early return (barrier above); stores guarded
    int r0 = tile * 16;
    int mrow = lane & 15;
    int kgrp = lane >> 4;  // 0..3

    int arow_i = r0 + mrow;
    if (arow_i > n - 1) arow_i = n - 1;
    const unsigned short* arow = A + (size_t)arow_i * DIM + kgrp * 8;

    f32x4 acc[8];
#pragma unroll
    for (int t = 0; t < 8; ++t) acc[t] = (f32x4){0.f, 0.f, 0.f, 0.f};

#pragma unroll
    for (int kc = 0; kc < 4; ++kc) {
        bf16x8 af = *(const bf16x8*)(arow + kc * 32);
#pragma unroll
        for (int t = 0; t < 8; ++t) {
            bf16x8 bfv = *(const bf16x8*)&Wlds[(t * 16 + mrow) * 136 + kc * 32 + kgrp * 8];
            acc[t] = __builtin_amdgcn_mfma_f32_16x16x32_bf16(af, bfv, acc[t], 0, 0, 0);
        }
    }

    // D layout: row = r0 + kgrp*4 + reg, col = t*16 + mrow
    // plane q = t>>1, within-plane col c = (t&1)*16 + mrow
    float dv[4];
#pragma unroll
    for (int reg = 0; reg < 4; ++reg) {
        int rr = r0 + kgrp * 4 + reg;
        dv[reg] = (rr < n) ? dinv[rr] : 0.f;
    }
#pragma unroll
    for (int t = 0; t < 8; ++t) {
        int q = t >> 1;
        int c = (t & 1) * 16 + mrow;
#pragma unroll
        for (int reg = 0; reg < 4; ++reg) {
            int row = r0 + kgrp * 4 + reg;
            if (row < n) {
                H[((size_t)q * n + row) * 32 + c] = f2bf(acc[t][reg] * dv[reg]);
            }
        }
    }
}

// --------------------- XCD-pinned plane-major gather, 16-batched loads
// Plane q (n*64B = 3.2 MB) is processed ONLY by blocks with blockIdx%8 in
// {2q,2q+1} -> on the %8 round-robin XCD mapping each XCD touches exactly one
// plane, which fits its 4 MiB L2 (fills ~3.2 MB once, then hits).
// Wave = 4 nodes x 16 lanes. Agg written with nontemporal stores so the
// write stream doesn't evict the resident plane.
__global__ __launch_bounds__(256) void gatherq_kernel(const int* __restrict__ rowptr,
                                                      const unsigned short* __restrict__ colsrc,
                                                      const unsigned int* __restrict__ H32,
                                                      unsigned int* __restrict__ agg32,
                                                      int n) {
    int b = blockIdx.x;
    int q = (b & 7) >> 1;                  // plane pinned to XCD pair
    int i = (b >> 3) * 2 + (b & 1);        // node-group index
    int wid = threadIdx.x >> 6;
    int lane = threadIdx.x & 63;
    int g = lane >> 4;                     // node slot within wave
    int t = lane & 15;
    int r = i * 16 + wid * 4 + g;
    if (r >= n) return;

    const unsigned int* Hq = H32 + (size_t)q * n * 16;

    unsigned int hv = Hq[(size_t)r * 16 + t];   // self-loop (plane-local)
    float ax = bf2f_lo(hv), ay = bf2f_hi(hv);

    int p = rowptr[r];
    int p1 = rowptr[r + 1];
    int gbase = g << 4;
    while (p < p1) {
        int cnt = p1 - p;
        if (cnt > 16) cnt = 16;
        int gi = p + t;
        gi = gi < p1 ? gi : p1 - 1;        // clamp: valid duplicate
        int idxv = (int)colsrc[gi];        // 16 edges of this node per group

        unsigned int h[16];
#pragma unroll
        for (int j = 0; j < 16; ++j) {
            int s = __shfl(idxv, gbase + j);   // own-group broadcast
            h[j] = Hq[(size_t)s * 16 + t];     // plane-local: L2-resident
        }
#pragma unroll
        for (int j = 0; j < 16; ++j) {
            bool act = (j < cnt);              // group-uniform; cndmask
            ax += act ? bf2f_lo(h[j]) : 0.f;
            ay += act ? bf2f_hi(h[j]) : 0.f;
        }
        p += cnt;
    }

    unsigned int pk = (unsigned int)f2bf(ax) | ((unsigned int)f2bf(ay) << 16);
    __builtin_nontemporal_store(pk, &agg32[((size_t)q * n + r) * 16 + t]);
}

// ------------------------------------------- dinv*agg + bias + LN (+ReLU)
// one wave per node; agg plane-major; lane = q*16 + t owns cols 2*lane,2*lane+1.
__global__ __launch_bounds__(256) void ln_kernel(const unsigned int* __restrict__ agg32,
                                                 const float* __restrict__ dinv,
                                                 const float* __restrict__ bias,
                                                 const float* __restrict__ gamma,
                                                 const float* __restrict__ beta,
                                                 unsigned int* __restrict__ out_bf,
                                                 float* __restrict__ out_f,
                                                 int n, int relu) {
    int wid = threadIdx.x >> 6;
    int lane = threadIdx.x & 63;
    int r = blockIdx.x * 4 + wid;
    if (r >= n) return;
    int q = lane >> 4;
    int t = lane & 15;

    float di = dinv[r];
    float2 bb = ((const float2*)bias)[lane];
    float2 gg = ((const float2*)gamma)[lane];
    float2 be = ((const float2*)beta)[lane];

    unsigned int av = __builtin_nontemporal_load(&agg32[((size_t)q * n + r) * 16 + t]);
    float vx = bf2f_lo(av) * di + bb.x;
    float vy = bf2f_hi(av) * di + bb.y;

    float s1 = vx + vy;
    float s2 = vx * vx + vy * vy;
#pragma unroll
    for (int off = 32; off > 0; off >>= 1) {
        s1 += __shfl_xor(s1, off);
        s2 += __shfl_xor(s2, off);
    }
    float mu = s1 * (1.f / 128.f);
    float var = s2 * (1.f / 128.f) - mu * mu;
    float rstd = rsqrtf(var + LN_EPS);

    float ox = (vx - mu) * rstd * gg.x + be.x;
    float oy = (vy - mu) * rstd * gg.y + be.y;
    if (relu) {
        ox = fmaxf(ox, 0.f);
        oy = fmaxf(oy, 0.f);
    }
    if (out_bf) {
        unsigned int pk = (unsigned int)f2bf(ox) | ((unsigned int)f2bf(oy) << 16);
        out_bf[(size_t)r * 64 + lane] = pk;
    } else {
        ((float2*)out_f)[(size_t)r * 64 + lane] = make_float2(ox, oy);
    }
}

// =============================================================================
extern "C" void kernel_launch(void* const* d_in, const int* in_sizes, int n_in,
                              void* d_out, int out_size, void* d_ws, size_t ws_size,
                              hipStream_t stream) {
    const float* x   = (const float*)d_in[0];
    const int*   ei  = (const int*)d_in[1];
    const float* W1  = (const float*)d_in[2];
    const float* b1  = (const float*)d_in[3];
    const float* g1  = (const float*)d_in[4];
    const float* be1 = (const float*)d_in[5];
    const float* W2  = (const float*)d_in[6];
    const float* b2  = (const float*)d_in[7];
    const float* g2  = (const float*)d_in[8];
    const float* be2 = (const float*)d_in[9];

    int n = in_sizes[0] / DIM;   // 50000
    int E = in_sizes[1] / 2;     // 600000
    const int* src = ei;
    const int* dst = ei + E;

    char* wp = (char*)d_ws;
    auto alloc = [&](size_t bytes) {
        void* p = (void*)wp;
        wp += (bytes + 255) & ~(size_t)255;
        return p;
    };
    float*          dinv   = (float*)alloc((size_t)n * 4);
    int*            counts = (int*)alloc((size_t)n * 4);
    int*            tmp    = (int*)alloc((size_t)n * 4);
    int*            rowptr = (int*)alloc((size_t)(n + 1) * 4);
    int*            cursor = (int*)alloc((size_t)n * 4);
    int*            bsums  = (int*)alloc(64 * 4);
    unsigned short* colsrc = (unsigned short*)alloc((size_t)E * 2);
    unsigned short* xb     = (unsigned short*)alloc((size_t)n * DIM * 2);
    unsigned short* Wt1    = (unsigned short*)alloc(128 * 128 * 2);
    unsigned short* Wt2    = (unsigned short*)alloc(128 * 128 * 2);
    unsigned short* H      = (unsigned short*)alloc((size_t)n * DIM * 2);
    unsigned short* Agg    = (unsigned short*)alloc((size_t)n * DIM * 2);
    unsigned short* Y1     = (unsigned short*)alloc((size_t)n * DIM * 2);

    hipMemsetAsync(counts, 0, (size_t)n * 4, stream);

    // --- conversions + degree count (one dispatch) ---
    int n4 = n * DIM / 4;
    int nx4b = (n4 + 255) / 256;
    int gE = (E + 255) / 256;
    cvt_count_kernel<<<nx4b + 128 + gE, 256, 0, stream>>>(x, xb, n4, nx4b, W1, W2, Wt1, Wt2,
                                                          dst, counts, E);

    // --- CSR build ---
    int nb1 = (n + 1023) / 1024;  // 49 for n=50000 (must be <= 64)
    scan1_kernel<<<nb1, 256, 0, stream>>>(counts, tmp, bsums, dinv, n);
    scan3_kernel<<<nb1, 256, 0, stream>>>(tmp, bsums, rowptr, cursor, n, E, nb1);
    fill_kernel<<<gE, 256, 0, stream>>>(src, dst, cursor, colsrc, E);

    int ntiles = (n + 15) / 16;
    int gG = (ntiles + 3) / 4;
    int nodeblocks = (n + 15) / 16;
    int nodeblocks2 = (nodeblocks + 1) & ~1;   // even
    int gQ = nodeblocks2 * 4;                  // 8 * (nodeblocks2/2)
    int gL = (n + 3) / 4;

    // --- layer 1 ---
    gemm_mfma_kernel<<<gG, 256, 0, stream>>>(xb, Wt1, dinv, H, n, ntiles);
    gatherq_kernel<<<gQ, 256, 0, stream>>>(rowptr, colsrc, (const unsigned int*)H,
                                           (unsigned int*)Agg, n);
    ln_kernel<<<gL, 256, 0, stream>>>((const unsigned int*)Agg, dinv, b1, g1, be1,
                                      (unsigned int*)Y1, nullptr, n, 1);

    // --- layer 2 ---
    gemm_mfma_kernel<<<gG, 256, 0, stream>>>(Y1, Wt2, dinv, H, n, ntiles);
    gatherq_kernel<<<gQ, 256, 0, stream>>>(rowptr, colsrc, (const unsigned int*)H,
                                           (unsigned int*)Agg, n);
    ln_kernel<<<gL, 256, 0, stream>>>((const unsigned int*)Agg, dinv, b2, g2, be2,
                                      nullptr, (float*)d_out, n, 0);
}

// Round 11
// 234.945 us; speedup vs baseline: 1.1160x; 1.1160x over previous
//
#include <hip/hip_runtime.h>

#define DIM 128
#define LN_EPS 1e-5f

typedef __attribute__((ext_vector_type(8))) short bf16x8;
typedef __attribute__((ext_vector_type(4))) float f32x4;

static __device__ __forceinline__ unsigned short f2bf(float f) {
    unsigned int u = __builtin_bit_cast(unsigned int, f);
    u += 0x7fffu + ((u >> 16) & 1u);  // round-to-nearest-even
    return (unsigned short)(u >> 16);
}
static __device__ __forceinline__ float bf2f_lo(unsigned int u) {
    return __builtin_bit_cast(float, u << 16);
}
static __device__ __forceinline__ float bf2f_hi(unsigned int u) {
    return __builtin_bit_cast(float, u & 0xffff0000u);
}

// --------------------- fused: W transpose+cvt, degree count (x cvt now in gemm1)
__global__ __launch_bounds__(256) void wt_count_kernel(const float* __restrict__ W1,
                                                       const float* __restrict__ W2,
                                                       unsigned short* __restrict__ Wt1,
                                                       unsigned short* __restrict__ Wt2,
                                                       const int* __restrict__ dst,
                                                       int* __restrict__ counts, int E) {
    int b = blockIdx.x;
    if (b < 128) {
        int elem = b * 256 + threadIdx.x;  // [0, 32768)
        int which = elem >> 14;
        int rest = elem & 16383;
        int c = rest >> 7;
        int k = rest & 127;
        const float* W = which ? W2 : W1;
        unsigned short* Wt = which ? Wt2 : Wt1;
        Wt[c * 128 + k] = f2bf(W[k * 128 + c]);
    } else {
        int e = (b - 128) * 256 + threadIdx.x;
        if (e < E) atomicAdd(&counts[dst[e]], 1);
    }
}

// ------------------------------------------------- scan pass 1 (+dinv compute)
__global__ __launch_bounds__(256) void scan1_kernel(const int* __restrict__ counts,
                                                    int* __restrict__ tmp,
                                                    int* __restrict__ bsums,
                                                    float* __restrict__ dinv, int n) {
    __shared__ int ts[256];
    int tid = threadIdx.x;
    int base = blockIdx.x * 1024 + tid * 4;
    int v[4];
#pragma unroll
    for (int j = 0; j < 4; ++j) {
        int i = base + j;
        v[j] = (i < n) ? counts[i] : 0;
        if (i < n) dinv[i] = rsqrtf((float)(v[j] + 1));  // +1 self-loop
    }
    int s = v[0] + v[1] + v[2] + v[3];
    ts[tid] = s;
    __syncthreads();
    for (int off = 1; off < 256; off <<= 1) {
        int t2 = (tid >= off) ? ts[tid - off] : 0;
        __syncthreads();
        ts[tid] += t2;
        __syncthreads();
    }
    int excl = ts[tid] - s;
    int pre = excl;
#pragma unroll
    for (int j = 0; j < 4; ++j) {
        int i = base + j;
        if (i < n) tmp[i] = pre;
        pre += v[j];
    }
    if (tid == 255) bsums[blockIdx.x] = ts[255];
}

// ------------------- scan pass 2+3 merged
__global__ __launch_bounds__(256) void scan3_kernel(const int* __restrict__ tmp,
                                                    const int* __restrict__ bsums,
                                                    int* __restrict__ rowptr,
                                                    int* __restrict__ cursor,
                                                    int n, int E, int nb) {
    __shared__ int s_add;
    if (threadIdx.x < 64) {
        int lane = threadIdx.x;
        int v = (lane < nb) ? bsums[lane] : 0;
        int x = v;
#pragma unroll
        for (int off = 1; off < 64; off <<= 1) {
            int y = __shfl_up(x, off);
            if (lane >= off) x += y;
        }
        int excl = x - v;
        int mine = __builtin_amdgcn_readlane(excl, blockIdx.x);
        if (lane == 0) s_add = mine;
    }
    __syncthreads();
    int add = s_add;
    int base = blockIdx.x * 1024 + threadIdx.x * 4;
#pragma unroll
    for (int j = 0; j < 4; ++j) {
        int i = base + j;
        if (i < n) {
            int val = tmp[i] + add;
            rowptr[i] = val;
            cursor[i] = val;
        }
    }
    if (blockIdx.x == 0 && threadIdx.x == 0) rowptr[n] = E;
}

// ---------------------------------------------------------------- CSR fill
__global__ __launch_bounds__(256) void fill_kernel(const int* __restrict__ src,
                                                   const int* __restrict__ dst,
                                                   int* __restrict__ cursor,
                                                   unsigned short* __restrict__ colsrc, int E) {
    int e = blockIdx.x * 256 + threadIdx.x;
    if (e < E) {
        int p = atomicAdd(&cursor[dst[e]], 1);
        colsrc[p] = (unsigned short)src[e];
    }
}

// ------------------------------------- MFMA GEMM, fp32 A (layer 1: reads x)
// Converts x rows to bf16 in registers (each row read exactly once).
__global__ __launch_bounds__(256) void gemm_mfma_f32_kernel(const float* __restrict__ A,
                                                            const unsigned short* __restrict__ Bt,
                                                            const float* __restrict__ dinv,
                                                            unsigned short* __restrict__ H,
                                                            int n, int ntiles) {
    __shared__ unsigned short Wlds[128 * 136];
    for (int u = threadIdx.x; u < 2048; u += 256) {
        int row = u >> 4;
        int sub = u & 15;
        *(bf16x8*)&Wlds[row * 136 + sub * 8] = *(const bf16x8*)(Bt + row * 128 + sub * 8);
    }
    __syncthreads();

    int wid = threadIdx.x >> 6;
    int lane = threadIdx.x & 63;
    int tile = blockIdx.x * 4 + wid;
    if (tile >= ntiles) tile = ntiles - 1;
    int r0 = tile * 16;
    int mrow = lane & 15;
    int kgrp = lane >> 4;

    int arow_i = r0 + mrow;
    if (arow_i > n - 1) arow_i = n - 1;
    const float* arow = A + (size_t)arow_i * DIM + kgrp * 8;

    f32x4 acc[8];
#pragma unroll
    for (int t = 0; t < 8; ++t) acc[t] = (f32x4){0.f, 0.f, 0.f, 0.f};

#pragma unroll
    for (int kc = 0; kc < 4; ++kc) {
        float4 v0 = *(const float4*)(arow + kc * 32);
        float4 v1 = *(const float4*)(arow + kc * 32 + 4);
        bf16x8 af;
        af[0] = (short)f2bf(v0.x); af[1] = (short)f2bf(v0.y);
        af[2] = (short)f2bf(v0.z); af[3] = (short)f2bf(v0.w);
        af[4] = (short)f2bf(v1.x); af[5] = (short)f2bf(v1.y);
        af[6] = (short)f2bf(v1.z); af[7] = (short)f2bf(v1.w);
#pragma unroll
        for (int t = 0; t < 8; ++t) {
            bf16x8 bfv = *(const bf16x8*)&Wlds[(t * 16 + mrow) * 136 + kc * 32 + kgrp * 8];
            acc[t] = __builtin_amdgcn_mfma_f32_16x16x32_bf16(af, bfv, acc[t], 0, 0, 0);
        }
    }

    float dv[4];
#pragma unroll
    for (int reg = 0; reg < 4; ++reg) {
        int rr = r0 + kgrp * 4 + reg;
        dv[reg] = (rr < n) ? dinv[rr] : 0.f;
    }
#pragma unroll
    for (int t = 0; t < 8; ++t) {
#pragma unroll
        for (int reg = 0; reg < 4; ++reg) {
            int row = r0 + kgrp * 4 + reg;
            if (row < n) {
                int col = t * 16 + mrow;
                H[(size_t)row * DIM + col] = f2bf(acc[t][reg] * dv[reg]);
            }
        }
    }
}

// ------------------------------------- MFMA GEMM, bf16 A (layer 2: reads Y1)
__global__ __launch_bounds__(256) void gemm_mfma_kernel(const unsigned short* __restrict__ A,
                                                        const unsigned short* __restrict__ Bt,
                                                        const float* __restrict__ dinv,
                                                        unsigned short* __restrict__ H,
                                                        int n, int ntiles) {
    __shared__ unsigned short Wlds[128 * 136];
    for (int u = threadIdx.x; u < 2048; u += 256) {
        int row = u >> 4;
        int sub = u & 15;
        *(bf16x8*)&Wlds[row * 136 + sub * 8] = *(const bf16x8*)(Bt + row * 128 + sub * 8);
    }
    __syncthreads();

    int wid = threadIdx.x >> 6;
    int lane = threadIdx.x & 63;
    int tile = blockIdx.x * 4 + wid;
    if (tile >= ntiles) tile = ntiles - 1;
    int r0 = tile * 16;
    int mrow = lane & 15;
    int kgrp = lane >> 4;

    int arow_i = r0 + mrow;
    if (arow_i > n - 1) arow_i = n - 1;
    const unsigned short* arow = A + (size_t)arow_i * DIM + kgrp * 8;

    f32x4 acc[8];
#pragma unroll
    for (int t = 0; t < 8; ++t) acc[t] = (f32x4){0.f, 0.f, 0.f, 0.f};

#pragma unroll
    for (int kc = 0; kc < 4; ++kc) {
        bf16x8 af = *(const bf16x8*)(arow + kc * 32);
#pragma unroll
        for (int t = 0; t < 8; ++t) {
            bf16x8 bfv = *(const bf16x8*)&Wlds[(t * 16 + mrow) * 136 + kc * 32 + kgrp * 8];
            acc[t] = __builtin_amdgcn_mfma_f32_16x16x32_bf16(af, bfv, acc[t], 0, 0, 0);
        }
    }

    float dv[4];
#pragma unroll
    for (int reg = 0; reg < 4; ++reg) {
        int rr = r0 + kgrp * 4 + reg;
        dv[reg] = (rr < n) ? dinv[rr] : 0.f;
    }
#pragma unroll
    for (int t = 0; t < 8; ++t) {
#pragma unroll
        for (int reg = 0; reg < 4; ++reg) {
            int row = r0 + kgrp * 4 + reg;
            if (row < n) {
                int col = t * 16 + mrow;
                H[(size_t)row * DIM + col] = f2bf(acc[t][reg] * dv[reg]);
            }
        }
    }
}

// ------------------- gather + bias + LayerNorm (+ReLU), branchless 16-batched
// (R9 version: readlane/saddr loads, fused LN — the proven best gather)
__global__ __launch_bounds__(256) void gather_ln_kernel(const int* __restrict__ rowptr,
                                                        const unsigned short* __restrict__ colsrc,
                                                        const unsigned int* __restrict__ Hb,
                                                        const float* __restrict__ dinv,
                                                        const float* __restrict__ bias,
                                                        const float* __restrict__ gamma,
                                                        const float* __restrict__ beta,
                                                        unsigned int* __restrict__ out_bf,
                                                        float* __restrict__ out_f,
                                                        int n, int relu) {
    int wid = threadIdx.x >> 6;
    int lane = threadIdx.x & 63;
    int r = blockIdx.x * 4 + wid;
    if (r >= n) return;

    float di = dinv[r];
    float2 bb = ((const float2*)bias)[lane];
    float2 gg = ((const float2*)gamma)[lane];
    float2 be = ((const float2*)beta)[lane];

    unsigned int su = Hb[(size_t)r * 64 + lane];  // self-loop term (pre-scaled)
    float ax = bf2f_lo(su), ay = bf2f_hi(su);

    int p = rowptr[r];
    int p1 = rowptr[r + 1];
    while (p < p1) {
        int cnt = p1 - p;
        if (cnt > 16) cnt = 16;
        int gi = p + lane;
        gi = gi < p1 ? gi : p1 - 1;          // clamp: valid duplicate
        int idxv = (int)colsrc[gi];          // one coalesced load per chunk

        unsigned int h[16];
#pragma unroll
        for (int j = 0; j < 16; ++j) {
            int s = __builtin_amdgcn_readlane(idxv, j);  // SGPR-uniform index
            h[j] = Hb[(size_t)s * 64 + lane];            // saddr load
        }

#pragma unroll
        for (int j = 0; j < 16; ++j) {
            bool act = (j < cnt);            // cnt wave-uniform; cndmask, no branch
            ax += act ? bf2f_lo(h[j]) : 0.f;
            ay += act ? bf2f_hi(h[j]) : 0.f;
        }
        p += cnt;
    }

    float vx = ax * di + bb.x;
    float vy = ay * di + bb.y;

    float s1 = vx + vy;
    float s2 = vx * vx + vy * vy;
#pragma unroll
    for (int off = 32; off > 0; off >>= 1) {
        s1 += __shfl_xor(s1, off);
        s2 += __shfl_xor(s2, off);
    }
    float mu = s1 * (1.f / 128.f);
    float var = s2 * (1.f / 128.f) - mu * mu;
    float rstd = rsqrtf(var + LN_EPS);

    float ox = (vx - mu) * rstd * gg.x + be.x;
    float oy = (vy - mu) * rstd * gg.y + be.y;
    if (relu) {
        ox = fmaxf(ox, 0.f);
        oy = fmaxf(oy, 0.f);
    }
    if (out_bf) {
        unsigned int pk = (unsigned int)f2bf(ox) | ((unsigned int)f2bf(oy) << 16);
        out_bf[(size_t)r * 64 + lane] = pk;
    } else {
        ((float2*)out_f)[(size_t)r * 64 + lane] = make_float2(ox, oy);
    }
}

// =============================================================================
extern "C" void kernel_launch(void* const* d_in, const int* in_sizes, int n_in,
                              void* d_out, int out_size, void* d_ws, size_t ws_size,
                              hipStream_t stream) {
    const float* x   = (const float*)d_in[0];
    const int*   ei  = (const int*)d_in[1];
    const float* W1  = (const float*)d_in[2];
    const float* b1  = (const float*)d_in[3];
    const float* g1  = (const float*)d_in[4];
    const float* be1 = (const float*)d_in[5];
    const float* W2  = (const float*)d_in[6];
    const float* b2  = (const float*)d_in[7];
    const float* g2  = (const float*)d_in[8];
    const float* be2 = (const float*)d_in[9];

    int n = in_sizes[0] / DIM;   // 50000
    int E = in_sizes[1] / 2;     // 600000
    const int* src = ei;
    const int* dst = ei + E;

    char* wp = (char*)d_ws;
    auto alloc = [&](size_t bytes) {
        void* p = (void*)wp;
        wp += (bytes + 255) & ~(size_t)255;
        return p;
    };
    float*          dinv   = (float*)alloc((size_t)n * 4);
    int*            counts = (int*)alloc((size_t)n * 4);
    int*            tmp    = (int*)alloc((size_t)n * 4);
    int*            rowptr = (int*)alloc((size_t)(n + 1) * 4);
    int*            cursor = (int*)alloc((size_t)n * 4);
    int*            bsums  = (int*)alloc(64 * 4);
    unsigned short* colsrc = (unsigned short*)alloc((size_t)E * 2);
    unsigned short* Wt1    = (unsigned short*)alloc(128 * 128 * 2);
    unsigned short* Wt2    = (unsigned short*)alloc(128 * 128 * 2);
    unsigned short* H      = (unsigned short*)alloc((size_t)n * DIM * 2);
    unsigned short* Y1     = (unsigned short*)alloc((size_t)n * DIM * 2);

    hipMemsetAsync(counts, 0, (size_t)n * 4, stream);

    // --- W transpose + degree count (one dispatch; x cvt fused into gemm1) ---
    int gE = (E + 255) / 256;
    wt_count_kernel<<<128 + gE, 256, 0, stream>>>(W1, W2, Wt1, Wt2, dst, counts, E);

    // --- CSR build ---
    int nb1 = (n + 1023) / 1024;  // 49 for n=50000 (must be <= 64)
    scan1_kernel<<<nb1, 256, 0, stream>>>(counts, tmp, bsums, dinv, n);
    scan3_kernel<<<nb1, 256, 0, stream>>>(tmp, bsums, rowptr, cursor, n, E, nb1);
    fill_kernel<<<gE, 256, 0, stream>>>(src, dst, cursor, colsrc, E);

    int ntiles = (n + 15) / 16;
    int gG = (ntiles + 3) / 4;
    int gA = (n + 3) / 4;

    // --- layer 1 ---
    gemm_mfma_f32_kernel<<<gG, 256, 0, stream>>>(x, Wt1, dinv, H, n, ntiles);
    gather_ln_kernel<<<gA, 256, 0, stream>>>(rowptr, colsrc, (const unsigned int*)H, dinv,
                                             b1, g1, be1, (unsigned int*)Y1, nullptr, n, 1);

    // --- layer 2 ---
    gemm_mfma_kernel<<<gG, 256, 0, stream>>>(Y1, Wt2, dinv, H, n, ntiles);
    gather_ln_kernel<<<gA, 256, 0, stream>>>(rowptr, colsrc, (const unsigned int*)H, dinv,
                                             b2, g2, be2, nullptr, (float*)d_out, n, 0);
}

// Round 12
// 232.476 us; speedup vs baseline: 1.1279x; 1.0106x over previous
//
#include <hip/hip_runtime.h>

#define DIM 128
#define LN_EPS 1e-5f

typedef __attribute__((ext_vector_type(8))) short bf16x8;
typedef __attribute__((ext_vector_type(4))) float f32x4;

static __device__ __forceinline__ unsigned short f2bf(float f) {
    unsigned int u = __builtin_bit_cast(unsigned int, f);
    u += 0x7fffu + ((u >> 16) & 1u);  // round-to-nearest-even
    return (unsigned short)(u >> 16);
}
static __device__ __forceinline__ float bf2f_lo(unsigned int u) {
    return __builtin_bit_cast(float, u << 16);
}
static __device__ __forceinline__ float bf2f_hi(unsigned int u) {
    return __builtin_bit_cast(float, u & 0xffff0000u);
}

// --------------------- fused: W transpose+cvt, degree count
__global__ __launch_bounds__(256) void wt_count_kernel(const float* __restrict__ W1,
                                                       const float* __restrict__ W2,
                                                       unsigned short* __restrict__ Wt1,
                                                       unsigned short* __restrict__ Wt2,
                                                       const int* __restrict__ dst,
                                                       int* __restrict__ counts, int E) {
    int b = blockIdx.x;
    if (b < 128) {
        int elem = b * 256 + threadIdx.x;  // [0, 32768)
        int which = elem >> 14;
        int rest = elem & 16383;
        int c = rest >> 7;
        int k = rest & 127;
        const float* W = which ? W2 : W1;
        unsigned short* Wt = which ? Wt2 : Wt1;
        Wt[c * 128 + k] = f2bf(W[k * 128 + c]);
    } else {
        int e = (b - 128) * 256 + threadIdx.x;
        if (e < E) atomicAdd(&counts[dst[e]], 1);
    }
}

// ------------------------------------------------- scan pass 1 (+dinv compute)
__global__ __launch_bounds__(256) void scan1_kernel(const int* __restrict__ counts,
                                                    int* __restrict__ tmp,
                                                    int* __restrict__ bsums,
                                                    float* __restrict__ dinv, int n) {
    __shared__ int ts[256];
    int tid = threadIdx.x;
    int base = blockIdx.x * 1024 + tid * 4;
    int v[4];
#pragma unroll
    for (int j = 0; j < 4; ++j) {
        int i = base + j;
        v[j] = (i < n) ? counts[i] : 0;
        if (i < n) dinv[i] = rsqrtf((float)(v[j] + 1));  // +1 self-loop
    }
    int s = v[0] + v[1] + v[2] + v[3];
    ts[tid] = s;
    __syncthreads();
    for (int off = 1; off < 256; off <<= 1) {
        int t2 = (tid >= off) ? ts[tid - off] : 0;
        __syncthreads();
        ts[tid] += t2;
        __syncthreads();
    }
    int excl = ts[tid] - s;
    int pre = excl;
#pragma unroll
    for (int j = 0; j < 4; ++j) {
        int i = base + j;
        if (i < n) tmp[i] = pre;
        pre += v[j];
    }
    if (tid == 255) bsums[blockIdx.x] = ts[255];
}

// ------------------- scan pass 2+3 merged
__global__ __launch_bounds__(256) void scan3_kernel(const int* __restrict__ tmp,
                                                    const int* __restrict__ bsums,
                                                    int* __restrict__ rowptr,
                                                    int* __restrict__ cursor,
                                                    int n, int E, int nb) {
    __shared__ int s_add;
    if (threadIdx.x < 64) {
        int lane = threadIdx.x;
        int v = (lane < nb) ? bsums[lane] : 0;
        int x = v;
#pragma unroll
        for (int off = 1; off < 64; off <<= 1) {
            int y = __shfl_up(x, off);
            if (lane >= off) x += y;
        }
        int excl = x - v;
        int mine = __builtin_amdgcn_readlane(excl, blockIdx.x);
        if (lane == 0) s_add = mine;
    }
    __syncthreads();
    int add = s_add;
    int base = blockIdx.x * 1024 + threadIdx.x * 4;
#pragma unroll
    for (int j = 0; j < 4; ++j) {
        int i = base + j;
        if (i < n) {
            int val = tmp[i] + add;
            rowptr[i] = val;
            cursor[i] = val;
        }
    }
    if (blockIdx.x == 0 && threadIdx.x == 0) rowptr[n] = E;
}

// ---------------------------------------------------------------- CSR fill
__global__ __launch_bounds__(256) void fill_kernel(const int* __restrict__ src,
                                                   const int* __restrict__ dst,
                                                   int* __restrict__ cursor,
                                                   unsigned short* __restrict__ colsrc, int E) {
    int e = blockIdx.x * 256 + threadIdx.x;
    if (e < E) {
        int p = atomicAdd(&cursor[dst[e]], 1);
        colsrc[p] = (unsigned short)src[e];
    }
}

// ------------------------------------- MFMA GEMM, fp32 A (layer 1: reads x)
__global__ __launch_bounds__(256) void gemm_mfma_f32_kernel(const float* __restrict__ A,
                                                            const unsigned short* __restrict__ Bt,
                                                            const float* __restrict__ dinv,
                                                            unsigned short* __restrict__ H,
                                                            int n, int ntiles) {
    __shared__ unsigned short Wlds[128 * 136];
    for (int u = threadIdx.x; u < 2048; u += 256) {
        int row = u >> 4;
        int sub = u & 15;
        *(bf16x8*)&Wlds[row * 136 + sub * 8] = *(const bf16x8*)(Bt + row * 128 + sub * 8);
    }
    __syncthreads();

    int wid = threadIdx.x >> 6;
    int lane = threadIdx.x & 63;
    int tile = blockIdx.x * 4 + wid;
    if (tile >= ntiles) tile = ntiles - 1;
    int r0 = tile * 16;
    int mrow = lane & 15;
    int kgrp = lane >> 4;

    int arow_i = r0 + mrow;
    if (arow_i > n - 1) arow_i = n - 1;
    const float* arow = A + (size_t)arow_i * DIM + kgrp * 8;

    f32x4 acc[8];
#pragma unroll
    for (int t = 0; t < 8; ++t) acc[t] = (f32x4){0.f, 0.f, 0.f, 0.f};

#pragma unroll
    for (int kc = 0; kc < 4; ++kc) {
        float4 v0 = *(const float4*)(arow + kc * 32);
        float4 v1 = *(const float4*)(arow + kc * 32 + 4);
        bf16x8 af;
        af[0] = (short)f2bf(v0.x); af[1] = (short)f2bf(v0.y);
        af[2] = (short)f2bf(v0.z); af[3] = (short)f2bf(v0.w);
        af[4] = (short)f2bf(v1.x); af[5] = (short)f2bf(v1.y);
        af[6] = (short)f2bf(v1.z); af[7] = (short)f2bf(v1.w);
#pragma unroll
        for (int t = 0; t < 8; ++t) {
            bf16x8 bfv = *(const bf16x8*)&Wlds[(t * 16 + mrow) * 136 + kc * 32 + kgrp * 8];
            acc[t] = __builtin_amdgcn_mfma_f32_16x16x32_bf16(af, bfv, acc[t], 0, 0, 0);
        }
    }

    float dv[4];
#pragma unroll
    for (int reg = 0; reg < 4; ++reg) {
        int rr = r0 + kgrp * 4 + reg;
        dv[reg] = (rr < n) ? dinv[rr] : 0.f;
    }
#pragma unroll
    for (int t = 0; t < 8; ++t) {
#pragma unroll
        for (int reg = 0; reg < 4; ++reg) {
            int row = r0 + kgrp * 4 + reg;
            if (row < n) {
                int col = t * 16 + mrow;
                H[(size_t)row * DIM + col] = f2bf(acc[t][reg] * dv[reg]);
            }
        }
    }
}

// ------------------------------------- MFMA GEMM, bf16 A (layer 2: reads Y1)
__global__ __launch_bounds__(256) void gemm_mfma_kernel(const unsigned short* __restrict__ A,
                                                        const unsigned short* __restrict__ Bt,
                                                        const float* __restrict__ dinv,
                                                        unsigned short* __restrict__ H,
                                                        int n, int ntiles) {
    __shared__ unsigned short Wlds[128 * 136];
    for (int u = threadIdx.x; u < 2048; u += 256) {
        int row = u >> 4;
        int sub = u & 15;
        *(bf16x8*)&Wlds[row * 136 + sub * 8] = *(const bf16x8*)(Bt + row * 128 + sub * 8);
    }
    __syncthreads();

    int wid = threadIdx.x >> 6;
    int lane = threadIdx.x & 63;
    int tile = blockIdx.x * 4 + wid;
    if (tile >= ntiles) tile = ntiles - 1;
    int r0 = tile * 16;
    int mrow = lane & 15;
    int kgrp = lane >> 4;

    int arow_i = r0 + mrow;
    if (arow_i > n - 1) arow_i = n - 1;
    const unsigned short* arow = A + (size_t)arow_i * DIM + kgrp * 8;

    f32x4 acc[8];
#pragma unroll
    for (int t = 0; t < 8; ++t) acc[t] = (f32x4){0.f, 0.f, 0.f, 0.f};

#pragma unroll
    for (int kc = 0; kc < 4; ++kc) {
        bf16x8 af = *(const bf16x8*)(arow + kc * 32);
#pragma unroll
        for (int t = 0; t < 8; ++t) {
            bf16x8 bfv = *(const bf16x8*)&Wlds[(t * 16 + mrow) * 136 + kc * 32 + kgrp * 8];
            acc[t] = __builtin_amdgcn_mfma_f32_16x16x32_bf16(af, bfv, acc[t], 0, 0, 0);
        }
    }

    float dv[4];
#pragma unroll
    for (int reg = 0; reg < 4; ++reg) {
        int rr = r0 + kgrp * 4 + reg;
        dv[reg] = (rr < n) ? dinv[rr] : 0.f;
    }
#pragma unroll
    for (int t = 0; t < 8; ++t) {
#pragma unroll
        for (int reg = 0; reg < 4; ++reg) {
            int row = r0 + kgrp * 4 + reg;
            if (row < n) {
                int col = t * 16 + mrow;
                H[(size_t)row * DIM + col] = f2bf(acc[t][reg] * dv[reg]);
            }
        }
    }
}

// ------------- DUAL-NODE gather + bias + LN (+ReLU), 16-batched per half-wave
// Each wave handles 2 nodes: lanes [0,32) -> node rA, lanes [32,64) -> node rB.
// Per row, 32 lanes x uint2 (8B) = 256B. Per chunk each half issues 16 row
// loads -> 32 rows in flight per wave (2x the single-node version).
__global__ __launch_bounds__(256) void gather_ln_kernel(const int* __restrict__ rowptr,
                                                        const unsigned short* __restrict__ colsrc,
                                                        const uint2* __restrict__ H2,
                                                        const float* __restrict__ dinv,
                                                        const float* __restrict__ bias,
                                                        const float* __restrict__ gamma,
                                                        const float* __restrict__ beta,
                                                        uint2* __restrict__ out_bf,
                                                        float* __restrict__ out_f,
                                                        int n, int relu) {
    int wid = threadIdx.x >> 6;
    int lane = threadIdx.x & 63;
    int half = lane >> 5;           // 0 or 1: which node
    int hl = lane & 31;             // lane within half
    int r = blockIdx.x * 8 + wid * 2 + half;
    int valid = (r < n);
    int rc = valid ? r : (n - 1);

    float di = dinv[rc];
    float4 bb = ((const float4*)bias)[hl];
    float4 gg = ((const float4*)gamma)[hl];
    float4 be = ((const float4*)beta)[hl];

    uint2 su = H2[(size_t)rc * 32 + hl];   // self-loop term (pre-scaled)
    float a0 = bf2f_lo(su.x), a1 = bf2f_hi(su.x);
    float a2 = bf2f_lo(su.y), a3 = bf2f_hi(su.y);

    int p0 = rowptr[rc];
    int p1 = rowptr[rc + 1];
    int deg = p1 - p0;
    // max degree across the two halves -> uniform chunk count
    int maxd = max(deg, __shfl_xor(deg, 32));
    int nchunks = (maxd + 15) >> 4;
    int hbase = half << 5;

    for (int c = 0; c < nchunks; ++c) {
        int cbase = c * 16;
        int gi = p0 + cbase + hl;
        gi = gi < p1 ? gi : p1 - 1;        // clamp: valid duplicate
        int idxv = (int)colsrc[gi];        // own half's 16 edges in lanes 0..15

        uint2 h[16];
#pragma unroll
        for (int j = 0; j < 16; ++j) {
            int s = __shfl(idxv, hbase + j);   // broadcast within own half
            h[j] = H2[(size_t)s * 32 + hl];
        }
#pragma unroll
        for (int j = 0; j < 16; ++j) {
            bool act = (cbase + j < deg);      // half-uniform; cndmask
            a0 += act ? bf2f_lo(h[j].x) : 0.f;
            a1 += act ? bf2f_hi(h[j].x) : 0.f;
            a2 += act ? bf2f_lo(h[j].y) : 0.f;
            a3 += act ? bf2f_hi(h[j].y) : 0.f;
        }
    }

    float v0 = a0 * di + bb.x;
    float v1 = a1 * di + bb.y;
    float v2 = a2 * di + bb.z;
    float v3 = a3 * di + bb.w;

    float s1 = v0 + v1 + v2 + v3;
    float s2 = v0 * v0 + v1 * v1 + v2 * v2 + v3 * v3;
#pragma unroll
    for (int off = 16; off > 0; off >>= 1) {   // reduce within 32-lane half
        s1 += __shfl_xor(s1, off);
        s2 += __shfl_xor(s2, off);
    }
    float mu = s1 * (1.f / 128.f);
    float var = s2 * (1.f / 128.f) - mu * mu;
    float rstd = rsqrtf(var + LN_EPS);

    float o0 = (v0 - mu) * rstd * gg.x + be.x;
    float o1 = (v1 - mu) * rstd * gg.y + be.y;
    float o2 = (v2 - mu) * rstd * gg.z + be.z;
    float o3 = (v3 - mu) * rstd * gg.w + be.w;
    if (relu) {
        o0 = fmaxf(o0, 0.f); o1 = fmaxf(o1, 0.f);
        o2 = fmaxf(o2, 0.f); o3 = fmaxf(o3, 0.f);
    }
    if (valid) {
        if (out_bf) {
            uint2 pk;
            pk.x = (unsigned int)f2bf(o0) | ((unsigned int)f2bf(o1) << 16);
            pk.y = (unsigned int)f2bf(o2) | ((unsigned int)f2bf(o3) << 16);
            out_bf[(size_t)r * 32 + hl] = pk;
        } else {
            ((float4*)out_f)[(size_t)r * 32 + hl] = make_float4(o0, o1, o2, o3);
        }
    }
}

// =============================================================================
extern "C" void kernel_launch(void* const* d_in, const int* in_sizes, int n_in,
                              void* d_out, int out_size, void* d_ws, size_t ws_size,
                              hipStream_t stream) {
    const float* x   = (const float*)d_in[0];
    const int*   ei  = (const int*)d_in[1];
    const float* W1  = (const float*)d_in[2];
    const float* b1  = (const float*)d_in[3];
    const float* g1  = (const float*)d_in[4];
    const float* be1 = (const float*)d_in[5];
    const float* W2  = (const float*)d_in[6];
    const float* b2  = (const float*)d_in[7];
    const float* g2  = (const float*)d_in[8];
    const float* be2 = (const float*)d_in[9];

    int n = in_sizes[0] / DIM;   // 50000
    int E = in_sizes[1] / 2;     // 600000
    const int* src = ei;
    const int* dst = ei + E;

    char* wp = (char*)d_ws;
    auto alloc = [&](size_t bytes) {
        void* p = (void*)wp;
        wp += (bytes + 255) & ~(size_t)255;
        return p;
    };
    float*          dinv   = (float*)alloc((size_t)n * 4);
    int*            counts = (int*)alloc((size_t)n * 4);
    int*            tmp    = (int*)alloc((size_t)n * 4);
    int*            rowptr = (int*)alloc((size_t)(n + 1) * 4);
    int*            cursor = (int*)alloc((size_t)n * 4);
    int*            bsums  = (int*)alloc(64 * 4);
    unsigned short* colsrc = (unsigned short*)alloc((size_t)E * 2);
    unsigned short* Wt1    = (unsigned short*)alloc(128 * 128 * 2);
    unsigned short* Wt2    = (unsigned short*)alloc(128 * 128 * 2);
    unsigned short* H      = (unsigned short*)alloc((size_t)n * DIM * 2);
    unsigned short* Y1     = (unsigned short*)alloc((size_t)n * DIM * 2);

    hipMemsetAsync(counts, 0, (size_t)n * 4, stream);

    // --- W transpose + degree count (one dispatch) ---
    int gE = (E + 255) / 256;
    wt_count_kernel<<<128 + gE, 256, 0, stream>>>(W1, W2, Wt1, Wt2, dst, counts, E);

    // --- CSR build ---
    int nb1 = (n + 1023) / 1024;  // 49 for n=50000 (must be <= 64)
    scan1_kernel<<<nb1, 256, 0, stream>>>(counts, tmp, bsums, dinv, n);
    scan3_kernel<<<nb1, 256, 0, stream>>>(tmp, bsums, rowptr, cursor, n, E, nb1);
    fill_kernel<<<gE, 256, 0, stream>>>(src, dst, cursor, colsrc, E);

    int ntiles = (n + 15) / 16;
    int gG = (ntiles + 3) / 4;
    int gA = (n + 7) / 8;   // 8 nodes per block (4 waves x 2 nodes)

    // --- layer 1 ---
    gemm_mfma_f32_kernel<<<gG, 256, 0, stream>>>(x, Wt1, dinv, H, n, ntiles);
    gather_ln_kernel<<<gA, 256, 0, stream>>>(rowptr, colsrc, (const uint2*)H, dinv,
                                             b1, g1, be1, (uint2*)Y1, nullptr, n, 1);

    // --- layer 2 ---
    gemm_mfma_kernel<<<gG, 256, 0, stream>>>(Y1, Wt2, dinv, H, n, ntiles);
    gather_ln_kernel<<<gA, 256, 0, stream>>>(rowptr, colsrc, (const uint2*)H, dinv,
                                             b2, g2, be2, nullptr, (float*)d_out, n, 0);
}